// Round 2
// baseline (34.645 us; speedup 1.0000x reference)
//
#include <hip/hip_runtime.h>

#define NQ 8
#define NL 4
#define BATCH 8192

// DPP lane-xor helpers (VALU-pipe, no lgkm wait).
// quad_perm[1,0,3,2]=0xB1 (xor1), quad_perm[2,3,0,1]=0x4E (xor2), row_ror:8=0x128 (xor8 within 16)
template <int CTRL>
__device__ __forceinline__ float fdpp(float v) {
    return __int_as_float(__builtin_amdgcn_update_dpp(0, __float_as_int(v), CTRL, 0xF, 0xF, true));
}
// xor4 within 16 lanes: ds_swizzle BitMode offset = (xor<<10)|and : 4<<10 | 0x1F
__device__ __forceinline__ float fswz4(float v) {
    return __int_as_float(__builtin_amdgcn_ds_swizzle(__float_as_int(v), 0x101F));
}

// One sample per 16 lanes: lane bits g3..g0 = state bits of wires 0-3,
// register index k in [0,16) = state bits of wires 4-7 (k3=wire4 ... k0=wire7).
__global__ __launch_bounds__(256) void qsim(const float* __restrict__ x,
                                            const float* __restrict__ w,
                                            float* __restrict__ out)
{
    const int tid = blockIdx.x * blockDim.x + threadIdx.x;
    const int grp = tid >> 4;              // sample index (grid exactly covers BATCH)
    const int g   = threadIdx.x & 15;      // lane within group

    // ---- encoding: |psi> is a real product state; build it directly ----
    const float4* xv = (const float4*)(x + grp * NQ);
    float4 x0 = xv[0], x1 = xv[1];
    float xe[NQ] = {x0.x, x0.y, x0.z, x0.w, x1.x, x1.y, x1.z, x1.w};
    float ce[NQ], se[NQ];
    #pragma unroll
    for (int i = 0; i < NQ; ++i) {
        float a = 0.5f * (xe[i] + w[i * 2]);
        ce[i] = __cosf(a);
        se[i] = __sinf(a);
    }
    float Pg = ((g & 8) ? se[0] : ce[0]) * ((g & 4) ? se[1] : ce[1])
             * ((g & 2) ? se[2] : ce[2]) * ((g & 1) ? se[3] : ce[3]);
    float p45[4] = {ce[4]*ce[5], ce[4]*se[5], se[4]*ce[5], se[4]*se[5]};
    float p67[4] = {ce[6]*ce[7], ce[6]*se[7], se[6]*ce[7], se[6]*se[7]};
    float q45[4];
    #pragma unroll
    for (int j = 0; j < 4; ++j) q45[j] = Pg * p45[j];
    float re[16], im[16];
    #pragma unroll
    for (int k = 0; k < 16; ++k) { re[k] = q45[(k >> 2) & 3] * p67[k & 3]; im[k] = 0.0f; }

    // ---- layers ----
    #pragma unroll 1
    for (int l = 0; l < NL; ++l) {
        // Coefficients (w is uniform -> scalar loads; trig on VALU once per layer).
        // Lane wires i<4: fused RY(theta)*RZ(phi): need ch=c*h, cz=c*z, sh=s*h, sz=s*z
        //   with c=cos(t/2), s=sin(t/2), h=cos(p/2), z=sin(p/2).
        // Reg wires: cy, sy (half-angle) and cf=cos(phi), sf=sin(phi) (relative-phase RZ).
        float LW[4][4], RW[4][4];
        #pragma unroll
        for (int i = 0; i < 4; ++i) {
            float th = w[(l * NQ + i) * 2 + 0], ph = w[(l * NQ + i) * 2 + 1];
            float c = __cosf(0.5f * th), s = __sinf(0.5f * th);
            float h = __cosf(0.5f * ph), z = __sinf(0.5f * ph);
            LW[i][0] = c * h; LW[i][1] = c * z; LW[i][2] = s * h; LW[i][3] = s * z;
        }
        #pragma unroll
        for (int i = 0; i < 4; ++i) {
            float th = w[(l * NQ + 4 + i) * 2 + 0], ph = w[(l * NQ + 4 + i) * 2 + 1];
            RW[i][0] = __cosf(0.5f * th); RW[i][1] = __sinf(0.5f * th);
            RW[i][2] = __cosf(ph);        RW[i][3] = __sinf(ph);
        }

        // CNOT(0,1),(1,2),(2,3): fused lane permutation src = g ^ (g>>1)
        const int src = (threadIdx.x & 48) | ((g ^ (g >> 1)) & 15);
        float tr[16], ti[16];
        #pragma unroll
        for (int k = 0; k < 16; ++k) {
            tr[k] = __shfl(re[k], src, 64);
            ti[k] = __shfl(im[k], src, 64);
        }
        // CNOT(3,4) folded with reg-Gray renaming (CNOT 4,5 / 5,6 / 6,7):
        // new[k] = tr[(k ^ (k>>1)) ^ (g0 ? 8 : 0)]
        const bool cc = (g & 1);
        #pragma unroll
        for (int k = 0; k < 16; ++k) {
            int s0 = k ^ (k >> 1);
            re[k] = cc ? tr[s0 ^ 8] : tr[s0];
            im[k] = cc ? ti[s0 ^ 8] : ti[s0];
        }
        // CNOT(7,0): control = reg bit k0, target = lane bit g3 (xor8 -> DPP ror8)
        #pragma unroll
        for (int k = 1; k < 16; k += 2) {
            re[k] = fdpp<0x128>(re[k]);
            im[k] = fdpp<0x128>(im[k]);
        }

        // Fused RZ+RY on lane wires 0..3.
        // own-coeff A = (ch, +-cz), partner-coeff B = (+-sh, -sz); sign by own lane bit.
        #pragma unroll
        for (int i = 0; i < 4; ++i) {
            const int mg = 8 >> i;
            const float Ar = LW[i][0];
            const float sz = LW[i][3];
            const float Ai = (g & mg) ? LW[i][1] : -LW[i][1];
            const float Br = (g & mg) ? LW[i][2] : -LW[i][2];
            #pragma unroll
            for (int k = 0; k < 16; ++k) {
                float br, bi;
                if (mg == 8)      { br = fdpp<0x128>(re[k]); bi = fdpp<0x128>(im[k]); }
                else if (mg == 4) { br = fswz4(re[k]);       bi = fswz4(im[k]); }
                else if (mg == 2) { br = fdpp<0x4E>(re[k]);  bi = fdpp<0x4E>(im[k]); }
                else              { br = fdpp<0xB1>(re[k]);  bi = fdpp<0xB1>(im[k]); }
                float ar = re[k], ai = im[k];
                re[k] = Ar * ar - Ai * ai + Br * br + sz * bi;
                im[k] = Ar * ai + Ai * ar + Br * bi - sz * br;
            }
        }

        // Reg wires 4..7: RZ = diag(1, e^{i phi}) (global phase dropped), then RY.
        #pragma unroll
        for (int i = 0; i < 4; ++i) {
            const int mk = 8 >> i;
            const float cy = RW[i][0], sy = RW[i][1], cf = RW[i][2], sf = RW[i][3];
            #pragma unroll
            for (int k = 0; k < 16; ++k) {
                if (!(k & mk)) continue;
                float r = re[k], q = im[k];
                re[k] = r * cf - q * sf;
                im[k] = q * cf + r * sf;
            }
            #pragma unroll
            for (int k = 0; k < 16; ++k) {
                if (k & mk) continue;
                int k1 = k | mk;
                float ar = re[k], ai = im[k], br = re[k1], bi = im[k1];
                re[k]  = cy * ar - sy * br;
                im[k]  = cy * ai - sy * bi;
                re[k1] = sy * ar + cy * br;
                im[k1] = sy * ai + cy * bi;
            }
        }
    }

    // ---- measurement ----
    float mt = 0.f, m4 = 0.f, m5 = 0.f, m6 = 0.f, m7 = 0.f;
    #pragma unroll
    for (int k = 0; k < 16; ++k) {
        float pv = re[k] * re[k] + im[k] * im[k];
        mt += pv;
        m4 += (k & 8) ? -pv : pv;
        m5 += (k & 4) ? -pv : pv;
        m6 += (k & 2) ? -pv : pv;
        m7 += (k & 1) ? -pv : pv;
    }
    float m0 = (g & 8) ? -mt : mt;
    float m1 = (g & 4) ? -mt : mt;
    float m2 = (g & 2) ? -mt : mt;
    float m3 = (g & 1) ? -mt : mt;
    // 16-lane sum: xor1, xor2 (DPP quads), xor4 (swizzle), xor8 (DPP ror8)
    #define RED(v) v += fdpp<0xB1>(v); v += fdpp<0x4E>(v); v += fswz4(v); v += fdpp<0x128>(v)
    RED(m0); RED(m1); RED(m2); RED(m3); RED(m4); RED(m5); RED(m6); RED(m7);
    #undef RED

    if (g == 0) {
        float4* o = (float4*)(out + grp * NQ);
        o[0] = make_float4(m0, m1, m2, m3);
        o[1] = make_float4(m4, m5, m6, m7);
    }
}

extern "C" void kernel_launch(void* const* d_in, const int* in_sizes, int n_in,
                              void* d_out, int out_size, void* d_ws, size_t ws_size,
                              hipStream_t stream)
{
    const float* x = (const float*)d_in[0];
    const float* w = (const float*)d_in[1];
    float* out = (float*)d_out;
    dim3 block(256);
    dim3 grid((BATCH * 16) / 256);   // 512 blocks, 16 lanes per sample
    qsim<<<grid, block, 0, stream>>>(x, w, out);
}